// Round 1
// baseline (2696.330 us; speedup 1.0000x reference)
//
#include <hip/hip_runtime.h>
#include <math.h>
#include <stdint.h>

#define DEV __device__ __forceinline__

// ---------------- problem constants ----------------
constexpr int Bz = 16, T = 512, D = 1024, H = 16, HS = 64, Lx = 4, DFF = 4096, NCn = 3;
constexpr int BT = Bz * T;  // 8192
constexpr long QSZ = (long)Bz * H * T * HS;  // elements per q/k/v tensor

typedef __attribute__((ext_vector_type(8))) short v8s;   // 8 x bf16 (4 VGPRs)
typedef __attribute__((ext_vector_type(4))) float v4f;   // MFMA accum

// ---------------- helpers ----------------
DEV uint16_t f2bf(float f) {            // round-to-nearest-even fp32 -> bf16
  uint32_t u = __float_as_uint(f);
  u += 0x7fff + ((u >> 16) & 1);
  return (uint16_t)(u >> 16);
}

DEV void async_copy16(const void* g, void* l) {
  // LDS base must be wave-uniform; HW deposits at base + lane*16
  __builtin_amdgcn_global_load_lds(
      (const __attribute__((address_space(1))) uint32_t*)g,
      (__attribute__((address_space(3))) uint32_t*)l, 16, 0, 0);
}

// ---- transpose + cast: in fp32 [R,C] batched z -> out bf16 [C,R] at (z/zdiv)*s1+(z%zdiv)*s2
__global__ void transpose_cast_kernel(const float* __restrict__ in, uint16_t* __restrict__ out,
                                      int R, int C, long s1, long s2, int zdiv) {
  __shared__ float tile[32][33];
  int zz = blockIdx.z;
  in += (long)zz * R * C;
  out += (long)(zz / zdiv) * s1 + (long)(zz % zdiv) * s2;
  int c0 = blockIdx.x * 32, r0 = blockIdx.y * 32;
  int tx = threadIdx.x, ty = threadIdx.y;  // 32 x 8
  for (int i = 0; i < 32; i += 8)
    tile[ty + i][tx] = in[(long)(r0 + ty + i) * C + (c0 + tx)];
  __syncthreads();
  for (int i = 0; i < 32; i += 8)
    out[(long)(c0 + ty + i) * R + (r0 + tx)] = f2bf(tile[tx][ty + i]);
}

// ---------------- embedding: h[b,t,:] = tok[x[b,t],:] + pos[t,:] ----------------
__global__ void embed_kernel(const int* __restrict__ x, const float* __restrict__ tok,
                             const float* __restrict__ pos, float* __restrict__ h) {
  int row = blockIdx.x;              // b*T + t
  int t = row & (T - 1);
  int id = x[row];
  const float4* tr = (const float4*)(tok + (long)id * D);
  const float4* pr = (const float4*)(pos + (long)t * D);
  float4* hr = (float4*)(h + (long)row * D);
  int i = threadIdx.x;               // 256 threads * 4 floats = 1024
  float4 a = tr[i], b = pr[i];
  hr[i] = make_float4(a.x + b.x, a.y + b.y, a.z + b.z, a.w + b.w);
}

// ---------------- layernorm over D=1024; one block per row ----------------
template <bool OUT_BF16>
__global__ void ln_kernel(const float* __restrict__ in, const float* __restrict__ g,
                          const float* __restrict__ b, void* __restrict__ out) {
  int row = blockIdx.x;
  int i = threadIdx.x;  // 256
  const float4* xr = (const float4*)(in + (long)row * D);
  float4 v = xr[i];
  float s = v.x + v.y + v.z + v.w;
  float s2 = v.x * v.x + v.y * v.y + v.z * v.z + v.w * v.w;
  for (int off = 32; off; off >>= 1) { s += __shfl_down(s, off); s2 += __shfl_down(s2, off); }
  __shared__ float sh1[4], sh2[4];
  int wid = i >> 6, lane = i & 63;
  if (lane == 0) { sh1[wid] = s; sh2[wid] = s2; }
  __syncthreads();
  s = sh1[0] + sh1[1] + sh1[2] + sh1[3];
  s2 = sh2[0] + sh2[1] + sh2[2] + sh2[3];
  float mu = s * (1.0f / D);
  float rstd = rsqrtf(s2 * (1.0f / D) - mu * mu + 1e-5f);
  float4 gv = ((const float4*)g)[i];
  float4 bv = ((const float4*)b)[i];
  float o0 = (v.x - mu) * rstd * gv.x + bv.x;
  float o1 = (v.y - mu) * rstd * gv.y + bv.y;
  float o2 = (v.z - mu) * rstd * gv.z + bv.z;
  float o3 = (v.w - mu) * rstd * gv.w + bv.w;
  if constexpr (OUT_BF16) {
    uint16_t* orow = (uint16_t*)out + (long)row * D;
    orow[4 * i + 0] = f2bf(o0); orow[4 * i + 1] = f2bf(o1);
    orow[4 * i + 2] = f2bf(o2); orow[4 * i + 3] = f2bf(o3);
  } else {
    ((float4*)((float*)out + (long)row * D))[i] = make_float4(o0, o1, o2, o3);
  }
}

// ---------- in-place scaled softmax: one wave per row of 512 bf16 (no LDS/barriers) ----------
__global__ void softmax_kernel(uint16_t* __restrict__ S) {
  int wid = threadIdx.x >> 6, lane = threadIdx.x & 63;
  long row = (long)blockIdx.x * 4 + wid;
  uint4* p = (uint4*)(S + row * T) + lane;   // 8 bf16 per lane
  uint4 u = *p;
  uint32_t w[4] = {u.x, u.y, u.z, u.w};
  float lo[4], hi[4];
  float m = -1e30f;
#pragma unroll
  for (int i = 0; i < 4; i++) {
    lo[i] = __uint_as_float(w[i] << 16) * 0.125f;          // * HS^-0.5
    hi[i] = __uint_as_float(w[i] & 0xffff0000u) * 0.125f;
    m = fmaxf(m, fmaxf(lo[i], hi[i]));
  }
  for (int off = 32; off; off >>= 1) m = fmaxf(m, __shfl_xor(m, off));
  float s = 0.f;
#pragma unroll
  for (int i = 0; i < 4; i++) {
    lo[i] = expf(lo[i] - m); hi[i] = expf(hi[i] - m);
    s += lo[i] + hi[i];
  }
  for (int off = 32; off; off >>= 1) s += __shfl_xor(s, off);
  float inv = 1.0f / s;
  uint4 o;
  uint32_t* ow = (uint32_t*)&o;
#pragma unroll
  for (int i = 0; i < 4; i++)
    ow[i] = (uint32_t)f2bf(lo[i] * inv) | ((uint32_t)f2bf(hi[i] * inv) << 16);
  *p = o;
}

enum { MQKV = 0, MBF = 1, MO = 2, MATOMIC = 3, MGELU = 4 };

// ---------------- legacy 128x128 MFMA GEMM (kept for S = qk^T and O = PV) ----------------
template <int BM, int BN, int WGM, int WGN, int MODE>
__global__ void gemm_kernel(const uint16_t* __restrict__ A, const uint16_t* __restrict__ Bt,
                            int M, int N, int K, int lda, int ldb,
                            long strideA, long strideB, long strideC,
                            const float* __restrict__ bias, void* __restrict__ Cout) {
  constexpr int WM = BM / WGM, WN = BN / WGN;
  constexpr int TM = WM / 16, TN = WN / 16;
  __shared__ __align__(16) uint16_t As[2][BM * 32];  // two k-panels of 32
  __shared__ __align__(16) uint16_t Bs[2][BN * 32];
  int kz = 0, batch = 0;
  if constexpr (MODE == MATOMIC) kz = blockIdx.z; else batch = blockIdx.z;
  A += (long)batch * strideA;
  Bt += (long)batch * strideB;
  const int kb0 = kz * K;
  int bm0 = blockIdx.x * BM, bn0 = blockIdx.y * BN;
  int tid = threadIdx.x, wid = tid >> 6, lane = tid & 63;
  int wm = wid / WGN, wn = wid % WGN;
  v4f acc[TM][TN] = {};

  const int laneRow = lane >> 2;                          // 16 rows per 1 KiB chunk
  const int laneB = ((lane & 3) ^ ((laneRow >> 1) & 3)) * 16;
  const int rl = lane & 15;
  const int cx16 = (rl * 4 + ((lane >> 4) ^ ((rl >> 1) & 3))) * 16;  // byte offset in 1 KiB block

  for (int k0 = kb0; k0 < kb0 + K; k0 += 64) {
    __syncthreads();  // previous iter done reading LDS
#pragma unroll
    for (int p = 0; p < 2; p++) {
      for (int c = wid; c < BM / 16; c += 4) {
        int row = bm0 + c * 16 + laneRow;
        async_copy16((const char*)(A + (long)row * lda + k0 + p * 32) + laneB,
                     (char*)As[p] + c * 1024);
      }
      for (int c = wid; c < BN / 16; c += 4) {
        int col = bn0 + c * 16 + laneRow;
        async_copy16((const char*)(Bt + (long)col * ldb + k0 + p * 32) + laneB,
                     (char*)Bs[p] + c * 1024);
      }
    }
    __syncthreads();  // drains vmcnt -> staged tiles visible

#pragma unroll
    for (int p = 0; p < 2; p++) {
      v8s af[TM], bfr[TN];
#pragma unroll
      for (int i = 0; i < TM; i++)
        af[i] = *(const v8s*)((const char*)As[p] + (wm * (WM / 16) + i) * 1024 + cx16);
#pragma unroll
      for (int j = 0; j < TN; j++)
        bfr[j] = *(const v8s*)((const char*)Bs[p] + (wn * (WN / 16) + j) * 1024 + cx16);
#pragma unroll
      for (int i = 0; i < TM; i++)
#pragma unroll
        for (int j = 0; j < TN; j++)
          acc[i][j] = __builtin_amdgcn_mfma_f32_16x16x32_bf16(af[i], bfr[j], acc[i][j], 0, 0, 0);
    }
  }

  // epilogue: C/D layout col=lane&15, row=(lane>>4)*4+r
#pragma unroll
  for (int i = 0; i < TM; i++) {
    int row0 = bm0 + wm * WM + i * 16 + (lane >> 4) * 4;
#pragma unroll
    for (int j = 0; j < TN; j++) {
      int col = bn0 + wn * WN + j * 16 + (lane & 15);
#pragma unroll
      for (int r = 0; r < 4; r++) {
        int row = row0 + r;
        float val = acc[i][j][r];
        if constexpr (MODE == MBF) {    // plain bf16, batched (scores)
          ((uint16_t*)Cout)[(long)batch * strideC + (long)row * N + col] = f2bf(val);
        } else if constexpr (MODE == MO) {     // attn out: [b,t,h,e]; batch=b*H+h
          int b = batch >> 4, hh = batch & 15;
          ((uint16_t*)Cout)[((long)(b * T + row) * H + hh) * HS + col] = f2bf(val);
        }
      }
    }
  }
}

// ---------------- 256x256 8-phase GEMM (T2 swizzle + T3/T4 counted vmcnt + T5 setprio) ----
// 8 waves (2M x 4N), 512 threads, BK=64, 1 block/CU (128 KiB LDS).
// LDS = 8 half-tile slots of 16 KiB (2-tile double buffer). Half order per tile:
//   slot (t&1)*4 + {0:B0, 1:B1, 2:A0, 3:A1}  (half-tile = 128 rows x 64 k, 16 x 1KiB blocks)
// Global half index h = 4t+part. Stage schedule: prologue h0..h5; loop tile t stages
// h=4t+6 (p1), 4t+7 (p2), 4t+8 (p3), 4t+9 (p4); vmcnt(4) once per tile at p4.
// Safety (verified per-phase): a slot staged at phase p was last ds_read at a phase
// ending >= 1 barrier earlier; vmcnt(4) leaves exactly the 2 newest halves (t+2's B0,B1)
// in flight, so all of tile t+1 has landed before its first read.
template <int MODE>
__global__ __launch_bounds__(512, 2) void gemm256_kernel(
    const uint16_t* __restrict__ A, const uint16_t* __restrict__ Bt,
    int mt, int N, int K, int lda, int ldb,
    const float* __restrict__ bias, void* __restrict__ Cout) {
  __shared__ __align__(16) uint16_t lds[8][8192];  // 128 KiB
  const int NT = K >> 6;  // K-tiles (requires NT >= 2; all call sites have NT >= 8)
  int kz = 0;
  if constexpr (MODE == MATOMIC) kz = blockIdx.z;
  const int kb0 = kz * K;

  // bijective XCD swizzle (m204): each XCD gets a contiguous chunk of wgids
  int nwg = gridDim.x, orig = blockIdx.x;
  int q = nwg >> 3, r = nwg & 7;
  int xcd = orig & 7, base = orig >> 3;
  int wgid = (xcd < r ? xcd * (q + 1) : r * (q + 1) + (xcd - r) * q) + base;
  int bm0 = (wgid % mt) * 256, bn0 = (wgid / mt) * 256;  // M fastest: B-panel stays in XCD L2

  int tid = threadIdx.x, wid = tid >> 6, lane = tid & 63;
  int wm = wid >> 2, wn = wid & 3;  // wave owns 128x64 of C

  // staging swizzle (identical XOR pattern to legacy kernel; verified 0 bank conflicts)
  const int laneRow = lane >> 2;
  const int g8 = ((lane & 3) ^ ((laneRow >> 1) & 3)) * 8;  // bf16 col offset within 32-col block
  const int rl = lane & 15;
  const int cx16 = (rl * 4 + ((lane >> 4) ^ ((rl >> 1) & 3))) * 16;

  auto stage = [&](int h) {  // stage half-tile h: 2 x global_load_lds per thread
    if (h >= 4 * NT) return;
    int th = h >> 2, part = h & 3;
    char* slot = (char*)lds[(th & 1) * 4 + part];
    int k0 = kb0 + th * 64;
    const uint16_t* src; int ld, r0;
    if (part < 2) { src = Bt; ld = ldb; r0 = bn0 + part * 128; }
    else          { src = A;  ld = lda; r0 = bm0 + (part - 2) * 128; }
#pragma unroll
    for (int c0 = 0; c0 < 2; c0++) {
      int c = wid + c0 * 8;                 // block 0..15 of this half
      int rg = c >> 1, kc = c & 1;          // 16-row group x 32-col group
      async_copy16(src + (long)(r0 + rg * 16 + laneRow) * ld + k0 + kc * 32 + g8,
                   slot + c * 1024);
    }
  };

  v4f acc[8][4] = {};

  // prologue: tile0 (B0,B1,A0,A1) + tile1 (B0,B1); leave newest 2 halves in flight
  for (int h = 0; h < 6; h++) stage(h);
  asm volatile("s_waitcnt vmcnt(4)" ::: "memory");  // tile0 fully landed
  __builtin_amdgcn_s_barrier();

  for (int t = 0; t < NT; t++) {
    const char* Aslot = (const char*)lds[(t & 1) * 4 + 2 + wm];
    const char* Bslot = (const char*)lds[(t & 1) * 4 + (wn >> 1)];
    const int jb = (wn & 1) * 4;  // wave's col-group base within its B-half
    v8s af[4][2], bf0[2][2], bf1[2][2];

    // ---- phase 1: read A rows 0-3 + B cols 0-1; stage t+1's A0; MFMA quad(0-3, 0-1)
#pragma unroll
    for (int i = 0; i < 4; i++)
#pragma unroll
      for (int kc = 0; kc < 2; kc++)
        af[i][kc] = *(const v8s*)(Aslot + (i * 2 + kc) * 1024 + cx16);
#pragma unroll
    for (int j = 0; j < 2; j++)
#pragma unroll
      for (int kc = 0; kc < 2; kc++)
        bf0[j][kc] = *(const v8s*)(Bslot + ((jb + j) * 2 + kc) * 1024 + cx16);
    stage(4 * t + 6);
    __builtin_amdgcn_s_barrier();
    asm volatile("s_waitcnt lgkmcnt(0)" ::: "memory");
    __builtin_amdgcn_s_setprio(1);
#pragma unroll
    for (int i = 0; i < 4; i++)
#pragma unroll
      for (int j = 0; j < 2; j++)
#pragma unroll
        for (int kc = 0; kc < 2; kc++)
          acc[i][j] = __builtin_amdgcn_mfma_f32_16x16x32_bf16(af[i][kc], bf0[j][kc], acc[i][j], 0, 0, 0);
    __builtin_amdgcn_s_setprio(0);
    __builtin_amdgcn_s_barrier();

    // ---- phase 2: read B cols 2-3; stage t+1's A1; MFMA quad(0-3, 2-3)
#pragma unroll
    for (int j = 0; j < 2; j++)
#pragma unroll
      for (int kc = 0; kc < 2; kc++)
        bf1[j][kc] = *(const v8s*)(Bslot + ((jb + 2 + j) * 2 + kc) * 1024 + cx16);
    stage(4 * t + 7);
    __builtin_amdgcn_s_barrier();
    asm volatile("s_waitcnt lgkmcnt(0)" ::: "memory");
    __builtin_amdgcn_s_setprio(1);
#pragma unroll
    for (int i = 0; i < 4; i++)
#pragma unroll
      for (int j = 0; j < 2; j++)
#pragma unroll
        for (int kc = 0; kc < 2; kc++)
          acc[i][2 + j] = __builtin_amdgcn_mfma_f32_16x16x32_bf16(af[i][kc], bf1[j][kc], acc[i][2 + j], 0, 0, 0);
    __builtin_amdgcn_s_setprio(0);
    __builtin_amdgcn_s_barrier();

    // ---- phase 3: read A rows 4-7 (reuse af regs); stage t+2's B0; MFMA quad(4-7, 2-3)
#pragma unroll
    for (int i = 0; i < 4; i++)
#pragma unroll
      for (int kc = 0; kc < 2; kc++)
        af[i][kc] = *(const v8s*)(Aslot + ((4 + i) * 2 + kc) * 1024 + cx16);
    stage(4 * t + 8);
    __builtin_amdgcn_s_barrier();
    asm volatile("s_waitcnt lgkmcnt(0)" ::: "memory");
    __builtin_amdgcn_s_setprio(1);
#pragma unroll
    for (int i = 0; i < 4; i++)
#pragma unroll
      for (int j = 0; j < 2; j++)
#pragma unroll
        for (int kc = 0; kc < 2; kc++)
          acc[4 + i][2 + j] = __builtin_amdgcn_mfma_f32_16x16x32_bf16(af[i][kc], bf1[j][kc], acc[4 + i][2 + j], 0, 0, 0);
    __builtin_amdgcn_s_setprio(0);
    __builtin_amdgcn_s_barrier();

    // ---- phase 4: stage t+2's B1; counted vmcnt; MFMA quad(4-7, 0-1)
    stage(4 * t + 9);
    if (t >= NT - 2) asm volatile("s_waitcnt vmcnt(0)" ::: "memory");
    else             asm volatile("s_waitcnt vmcnt(4)" ::: "memory");  // tile t+1 landed
    __builtin_amdgcn_s_barrier();
    asm volatile("s_waitcnt lgkmcnt(0)" ::: "memory");
    __builtin_amdgcn_s_setprio(1);
#pragma unroll
    for (int i = 0; i < 4; i++)
#pragma unroll
      for (int j = 0; j < 2; j++)
#pragma unroll
        for (int kc = 0; kc < 2; kc++)
          acc[4 + i][j] = __builtin_amdgcn_mfma_f32_16x16x32_bf16(af[i][kc], bf0[j][kc], acc[4 + i][j], 0, 0, 0);
    __builtin_amdgcn_s_setprio(0);
    __builtin_amdgcn_s_barrier();
  }

  // epilogue: C/D layout col=lane&15, row=(lane>>4)*4+r
#pragma unroll
  for (int i = 0; i < 8; i++) {
    int row0 = bm0 + wm * 128 + i * 16 + (lane >> 4) * 4;
#pragma unroll
    for (int j = 0; j < 4; j++) {
      int col = bn0 + wn * 64 + j * 16 + rl;
#pragma unroll
      for (int r = 0; r < 4; r++) {
        int row = row0 + r;
        float val = acc[i][j][r];
        if constexpr (MODE == MQKV) {          // fused qkv scatter
          int sel = col >> 10, c = col & 1023;
          int hh = c >> 6, e = c & 63;
          int b = row >> 9, tt = row & 511;
          long idx = (sel < 2) ? (((long)(b * H + hh) * T + tt) * HS + e)
                               : (((long)(b * H + hh) * HS + e) * T + tt);  // v transposed
          ((uint16_t*)Cout)[(long)sel * QSZ + idx] = f2bf(val);
        } else if constexpr (MODE == MATOMIC) {  // h += partial (+bias once)
          float add = val + ((kz == 0) ? bias[col] : 0.f);
          atomicAdd(&((float*)Cout)[(long)row * N + col], add);
        } else if constexpr (MODE == MGELU) {  // bf16 gelu(acc + bias)
          float xg = val + bias[col];
          float gl = 0.5f * xg * (1.0f + erff(xg * 0.70710678118f));
          ((uint16_t*)Cout)[(long)row * N + col] = f2bf(gl);
        }
      }
    }
  }
}

// ---------------- logits: out[b,c] = bout[c] + sum_i h[b,i] * Wout[i,c] ----------------
__global__ void logits_init(const float* __restrict__ bout, float* __restrict__ out) {
  int i = threadIdx.x;
  if (i < Bz * NCn) out[i] = bout[i % NCn];
}
__global__ void logits_kernel(const float* __restrict__ hf, const float* __restrict__ Wout,
                              float* __restrict__ out) {
  int b = blockIdx.y, c = blockIdx.z;
  long base = (long)blockIdx.x * 8192;  // T*D / 64 chunks
  const float* hv = hf + (long)b * T * D + base;
  const float* w = Wout + base * NCn + c;
  float s = 0.f;
  for (int i = threadIdx.x; i < 8192; i += 256) s += hv[i] * w[(long)i * NCn];
  for (int off = 32; off; off >>= 1) s += __shfl_down(s, off);
  __shared__ float sh[4];
  int wid = threadIdx.x >> 6, lane = threadIdx.x & 63;
  if (lane == 0) sh[wid] = s;
  __syncthreads();
  if (threadIdx.x == 0) atomicAdd(out + b * NCn + c, sh[0] + sh[1] + sh[2] + sh[3]);
}

// ---------------- host ----------------
extern "C" void kernel_launch(void* const* d_in, const int* in_sizes, int n_in,
                              void* d_out, int out_size, void* d_ws, size_t ws_size,
                              hipStream_t stream) {
  const int* x = (const int*)d_in[0];
  const float* tok = (const float*)d_in[1];
  const float* pos = (const float*)d_in[2];
  const float* Wq = (const float*)d_in[3];
  const float* Wk = (const float*)d_in[4];
  const float* Wv = (const float*)d_in[5];
  const float* Wproj = (const float*)d_in[6];
  const float* bproj = (const float*)d_in[7];
  const float* ln1g = (const float*)d_in[8];
  const float* ln1b = (const float*)d_in[9];
  const float* ln2g = (const float*)d_in[10];
  const float* ln2b = (const float*)d_in[11];
  const float* W1 = (const float*)d_in[12];
  const float* b1 = (const float*)d_in[13];
  const float* W2 = (const float*)d_in[14];
  const float* b2 = (const float*)d_in[15];
  const float* lnfg = (const float*)d_in[16];
  const float* lnfb = (const float*)d_in[17];
  const float* Wout = (const float*)d_in[18];
  const float* bout = (const float*)d_in[19];
  float* out = (float*)d_out;

  // workspace layout
  char* ws = (char*)d_ws;
  size_t off = 0;
  auto alloc = [&](size_t bytes) { char* p = ws + off; off += (bytes + 255) & ~(size_t)255; return p; };
  uint16_t* wqkvT = (uint16_t*)alloc((size_t)Lx * 3 * D * D * 2);  // [L][3*D][D]
  uint16_t* wpT = (uint16_t*)alloc((size_t)Lx * D * D * 2);
  uint16_t* w1T = (uint16_t*)alloc((size_t)Lx * D * DFF * 2);
  uint16_t* w2T = (uint16_t*)alloc((size_t)Lx * D * DFF * 2);
  float* h = (float*)alloc((size_t)BT * D * 4);
  uint16_t* z = (uint16_t*)alloc((size_t)BT * D * 2);
  uint16_t* qkv = (uint16_t*)alloc((size_t)3 * QSZ * 2);  // q | k | v^T contiguous
  uint16_t* Sb = (uint16_t*)alloc((size_t)Bz * H * T * T * 2);
  uint16_t* o = (uint16_t*)alloc((size_t)BT * D * 2);
  uint16_t* a1 = (uint16_t*)alloc((size_t)BT * DFF * 2);
  (void)ws_size; (void)in_sizes; (void)n_in; (void)out_size;

  uint16_t* q = qkv;
  uint16_t* kb = qkv + QSZ;
  uint16_t* vt = qkv + 2 * QSZ;

  dim3 tb(32, 8);
  // weights -> bf16 B^T layout. wqkvT rows: [0,1024)=q, [1024,2048)=k, [2048,3072)=v
  transpose_cast_kernel<<<dim3(HS / 32, D / 32, Lx * H), tb, 0, stream>>>(
      Wq, wqkvT, D, HS, 3L * D * D, (long)HS * D, H);
  transpose_cast_kernel<<<dim3(HS / 32, D / 32, Lx * H), tb, 0, stream>>>(
      Wk, wqkvT + (long)D * D, D, HS, 3L * D * D, (long)HS * D, H);
  transpose_cast_kernel<<<dim3(HS / 32, D / 32, Lx * H), tb, 0, stream>>>(
      Wv, wqkvT + 2L * D * D, D, HS, 3L * D * D, (long)HS * D, H);
  transpose_cast_kernel<<<dim3(D / 32, D / 32, Lx), tb, 0, stream>>>(
      Wproj, wpT, D, D, (long)D * D, 0, 1);
  transpose_cast_kernel<<<dim3(DFF / 32, D / 32, Lx), tb, 0, stream>>>(
      W1, w1T, D, DFF, (long)D * DFF, 0, 1);
  transpose_cast_kernel<<<dim3(D / 32, DFF / 32, Lx), tb, 0, stream>>>(
      W2, w2T, DFF, D, (long)D * DFF, 0, 1);

  embed_kernel<<<BT, 256, 0, stream>>>(x, tok, pos, h);

  constexpr int MT = BT / 256;  // 32 M-tiles

  for (int l = 0; l < Lx; l++) {
    const uint16_t* wqkv_l = wqkvT + (size_t)l * 3 * D * D;
    const uint16_t* wp_l = wpT + (size_t)l * D * D;
    const uint16_t* w1_l = w1T + (size_t)l * D * DFF;
    const uint16_t* w2_l = w2T + (size_t)l * D * DFF;

    ln_kernel<true><<<BT, 256, 0, stream>>>(h, ln1g + l * D, ln1b + l * D, z);

    // fused QKV: [8192,1024] x [3072,1024]^T  (256^2 8-phase, NT=16)
    gemm256_kernel<MQKV><<<dim3(MT * (3 * D / 256), 1, 1), 512, 0, stream>>>(
        z, wqkv_l, MT, 3 * D, D, D, D, nullptr, qkv);

    // S = q @ k^T per (b,h): M=N=512, K=64 -> single K-iteration (legacy kernel)
    gemm_kernel<128, 128, 2, 2, MBF><<<dim3(T / 128, T / 128, Bz * H), 256, 0, stream>>>(
        q, kb, T, T, HS, HS, HS, (long)T * HS, (long)T * HS, (long)T * T, nullptr, Sb);

    softmax_kernel<<<Bz * H * T / 4, 256, 0, stream>>>(Sb);

    // O = P @ V : M=512, N=64, K=512 (legacy kernel)
    gemm_kernel<128, 64, 4, 1, MO><<<dim3(T / 128, 1, Bz * H), 256, 0, stream>>>(
        Sb, vt, T, HS, T, T, T, (long)T * T, (long)HS * T, 0, nullptr, o);

    // h += o @ Wproj + bproj   (split-K=2, atomic; NT=8 per split)
    gemm256_kernel<MATOMIC><<<dim3(MT * (D / 256), 1, 2), 512, 0, stream>>>(
        o, wp_l, MT, D, D / 2, D, D, bproj + l * D, h);

    ln_kernel<true><<<BT, 256, 0, stream>>>(h, ln2g + l * D, ln2b + l * D, z);

    // a1 = gelu(z @ W1 + b1)  (NT=16)
    gemm256_kernel<MGELU><<<dim3(MT * (DFF / 256), 1, 1), 512, 0, stream>>>(
        z, w1_l, MT, DFF, D, D, D, b1 + l * DFF, a1);

    // h += a1 @ W2 + b2   (split-K=2, atomic; NT=32 per split)
    gemm256_kernel<MATOMIC><<<dim3(MT * (D / 256), 1, 2), 512, 0, stream>>>(
        a1, w2_l, MT, D, DFF / 2, DFF, DFF, b2 + l * D, h);
  }

  // final LN in-place (fp32), then logits
  ln_kernel<false><<<BT, 256, 0, stream>>>(h, lnfg, lnfb, h);
  logits_init<<<1, 64, 0, stream>>>(bout, out);
  logits_kernel<<<dim3(64, Bz, NCn), 256, 0, stream>>>(h, Wout, out);
}